// Round 9
// baseline (63.786 us; speedup 1.0000x reference)
//
#include <hip/hip_runtime.h>
#include <stdint.h>

// Problem constants: x (4, 8192, 512) f32, A/B (512, 64), h0 scalar.
#define NBATCH 4
#define LSEQ   8192
#define CH     512
#define ORDER  64
#define KTAP   256           // validated R3-R8: tail < 1e-5, threshold 5.86e-3

typedef _Float16 half8 __attribute__((ext_vector_type(8)));
typedef _Float16 f16x2 __attribute__((ext_vector_type(2)));
typedef float    f32x4 __attribute__((ext_vector_type(4)));

#define NW    9              // windows T0_w = 32w+15 cover t in [0,256) once/row
#define AFRAG_HALFS  ((size_t)CH * NW * 64 * 8)        // 4.7 MB
#define WS_NEED      (AFRAG_HALFS * 2)

// fir LDS geometry: xs[16 ch][1320 halves] (pad 1312->1320: stage-write 2-way),
// lds_out[16 ch][260 f32] ALIASED onto the same buffer (xs dead after MFMAs).
#define XSW   1320
#define XROWB 2640           // XSW * 2 bytes
#define LOW   260
#define LOWB  1040           // LOW * 4 bytes
#define SMEMB (16 * XROWB)   // 42240 B

__device__ __forceinline__ uint32_t packh2(_Float16 lo, _Float16 hi) {
    f16x2 v; v.x = lo; v.y = hi;
    return __builtin_bit_cast(uint32_t, v);
}

// ---------------------------------------------------------------------------
// Kernel 1: IIR impulse response -> per-channel MFMA A-fragments.
//   A_w[i][k] = Kx[32w+15+i-k], lane l: i=l&15, k=8*(l>>4)+e; h0 folded into
//   Kx[0]; Kx zero outside [0,KTAP). 4 channels/block, one wave each.
// ---------------------------------------------------------------------------
__global__ __launch_bounds__(256) void rtf_afrag(const float* __restrict__ A,
                                                 const float* __restrict__ B,
                                                 const float* __restrict__ h0,
                                                 _Float16* __restrict__ afr) {
    __shared__ float Ksh[4][KTAP];
    const int wv = threadIdx.x >> 6, lane = threadIdx.x & 63;
    const int c  = blockIdx.x * 4 + wv;
    const float a  = A[c * ORDER + lane];
    const float bc = B[c * ORDER + lane];
    const float h0v = h0[0];
    float s = 0.0f;
    for (int t = 0; t < KTAP; ++t) {
        const float s1 = __shfl(s, 0);
        const float bt = (t < ORDER) ? __shfl(bc, t) : 0.0f;
        const float y  = bt + s1;
        float su = __shfl_down(s, 1);
        if (lane == ORDER - 1) su = 0.0f;
        s = su - a * y;
        if (lane == 0) Ksh[wv][t] = (t == 0) ? (y + h0v) : y;
    }
    __syncthreads();
    const int i = lane & 15, g = lane >> 4;
    for (int w = 0; w < NW; ++w) {
        half8 hv;
#pragma unroll
        for (int e = 0; e < 8; ++e) {
            const int t = 32 * w + 15 + i - 8 * g - e;
            hv[e] = (_Float16)((t >= 0 && t < KTAP) ? Ksh[wv][t] : 0.0f);
        }
        *reinterpret_cast<half8*>(afr + ((size_t)(c * NW + w) * 64 + lane) * 8) = hv;
    }
}

// ---------------------------------------------------------------------------
// Kernel 2: FIR as banded-Toeplitz MFMA + gelu. Direct-from-x staging.
// Block = 16 ch x 1024 n (4 tiles of 256) x 1 batch. Grid 1024, chgrp-major
// XCD swizzle (A-frags L2-resident per XCD).
// Stage: x[bb][n0-271 .. n0+1040][16ch] f32 -> f16 pairs -> xs[ch][idx]
//   (idx = abs_row - (n0-271)); float4 loads (64B segments), packed b32
//   LDS writes (2-way, free). No global transpose pass needed.
// Main: w-outer/tile-inner, A-frag global (L2), B-frag ds_read_b128 1:1 MFMA.
// Epilogue per tile: gelu -> lds_out (ALIASES xs, f32x4 writes) -> lane
//   gathers 4 ch (4x b32, 2-way) -> one dwordx4 store (64B segments).
// ---------------------------------------------------------------------------
__global__ __launch_bounds__(256) void fir_mfma(const float* __restrict__ x,
                                                const _Float16* __restrict__ afr,
                                                float* __restrict__ out) {
    __shared__ __align__(16) char smem[SMEMB];
    const int gid     = blockIdx.x;
    const int logical = (gid & 7) * 128 + (gid >> 3);   // bijective (1024%8==0)
    const int chgrp   = logical >> 5;                   // 0..31 (XCD-local slab)
    const int rem     = logical & 31;
    const int bb      = rem >> 3;
    const int tg      = rem & 7;
    const int n0      = tg * 1024;

    // ---- stage: 656 row-pairs, thread = (pair slot, channel quad) ----
    {
        const int cg = threadIdx.x & 3;
        const int pr = threadIdx.x >> 2;
        const float* xsrc = x + (size_t)bb * LSEQ * CH + chgrp * 16 + cg * 4;
#pragma unroll
        for (int it = 0; it < 11; ++it) {
            const int p = pr + 64 * it;
            if (p < 656) {
                const int r0 = n0 - 271 + 2 * p;
                float4 v0 = {0.f, 0.f, 0.f, 0.f}, v1 = v0;
                if (r0 >= 0 && r0 < LSEQ)
                    v0 = *reinterpret_cast<const float4*>(xsrc + (size_t)r0 * CH);
                if (r0 + 1 >= 0 && r0 + 1 < LSEQ)
                    v1 = *reinterpret_cast<const float4*>(xsrc + (size_t)(r0 + 1) * CH);
                char* base = smem + (size_t)(cg * 4) * XROWB + 4 * p;
                *reinterpret_cast<uint32_t*>(base + 0 * XROWB) =
                    packh2((_Float16)v0.x, (_Float16)v1.x);
                *reinterpret_cast<uint32_t*>(base + 1 * XROWB) =
                    packh2((_Float16)v0.y, (_Float16)v1.y);
                *reinterpret_cast<uint32_t*>(base + 2 * XROWB) =
                    packh2((_Float16)v0.z, (_Float16)v1.z);
                *reinterpret_cast<uint32_t*>(base + 3 * XROWB) =
                    packh2((_Float16)v0.w, (_Float16)v1.w);
            }
        }
    }
    __syncthreads();

    const int wid = threadIdx.x >> 6, lane = threadIdx.x & 63;
    const int j = lane & 15, g = lane >> 4;
    const int c0 = chgrp * 16 + wid * 4;
    const _Float16* af = afr + (size_t)lane * 8;

    f32x4 acc[4][4];
#pragma unroll
    for (int ti = 0; ti < 4; ++ti)
#pragma unroll
        for (int q = 0; q < 4; ++q) acc[ti][q] = (f32x4){0.f, 0.f, 0.f, 0.f};

#pragma unroll
    for (int w = 0; w < NW; ++w) {
        half8 a[4];
#pragma unroll
        for (int q = 0; q < 4; ++q)
            a[q] = *reinterpret_cast<const half8*>(af + (size_t)((c0 + q) * NW + w) * 512);
        const int base = 16 * j + 8 * g - 32 * w + 256;   // xs idx of B-frag, tile 0
#pragma unroll
        for (int ti = 0; ti < 4; ++ti) {
#pragma unroll
            for (int q = 0; q < 4; ++q) {
                const half8 bv = *reinterpret_cast<const half8*>(
                    smem + (size_t)(wid * 4 + q) * XROWB + 2 * (base + 256 * ti));
                acc[ti][q] = __builtin_amdgcn_mfma_f32_16x16x32_f16(a[q], bv, acc[ti][q], 0, 0, 0);
            }
        }
    }

    // ---- epilogue: per tile, gelu -> lds_out (aliases xs) -> dwordx4 stores ----
    const int cq = threadIdx.x & 3;
    const int nq = threadIdx.x >> 2;       // 0..63
#pragma unroll
    for (int ti = 0; ti < 4; ++ti) {
        __syncthreads();                   // xs reads / previous-tile reads done
#pragma unroll
        for (int q = 0; q < 4; ++q) {
            f32x4 o;
#pragma unroll
            for (int r = 0; r < 4; ++r) {
                const float y  = acc[ti][q][r];
                const float m2 = y * y;
                const float wv = fmaf(m2, 0.14270963f, 1.5957691f);
                const float e  = __expf(y * wv);
                const float rc = __builtin_amdgcn_rcpf(e + 1.0f);
                o[r] = y - y * rc;
            }
            *reinterpret_cast<f32x4*>(smem + (size_t)(wid * 4 + q) * LOWB
                                      + 4 * (16 * j + 4 * g)) = o;
        }
        __syncthreads();
        float* ob = out + ((size_t)bb * LSEQ + n0 + ti * 256) * CH + chgrp * 16 + cq * 4;
#pragma unroll
        for (int it = 0; it < 4; ++it) {
            const int n = nq + 64 * it;
            float4 o;
            o.x = *reinterpret_cast<float*>(smem + (size_t)(cq * 4 + 0) * LOWB + 4 * n);
            o.y = *reinterpret_cast<float*>(smem + (size_t)(cq * 4 + 1) * LOWB + 4 * n);
            o.z = *reinterpret_cast<float*>(smem + (size_t)(cq * 4 + 2) * LOWB + 4 * n);
            o.w = *reinterpret_cast<float*>(smem + (size_t)(cq * 4 + 3) * LOWB + 4 * n);
            *reinterpret_cast<float4*>(ob + (size_t)n * CH) = o;
        }
    }
}

// ======================== FALLBACK (R5, proven 138us) =======================
#define RINGF 32
#define CPBF  256
__global__ __launch_bounds__(ORDER) void rtf_impulse_fb(const float* __restrict__ A,
                                                        const float* __restrict__ B,
                                                        const float* __restrict__ h0,
                                                        float* __restrict__ kt4) {
    const int c = blockIdx.x, lane = threadIdx.x;
    const float a = A[c * ORDER + lane], bc = B[c * ORDER + lane], h0v = h0[0];
    float s = 0.0f;
    for (int t = 0; t < KTAP; ++t) {
        const float s1 = __shfl(s, 0);
        const float bt = (t < ORDER) ? __shfl(bc, t) : 0.0f;
        const float y  = bt + s1;
        float su = __shfl_down(s, 1);
        if (lane == ORDER - 1) su = 0.0f;
        s = su - a * y;
        if (lane == 0) kt4[((size_t)(t >> 2) * CH + c) * 4 + (t & 3)] = (t == 0) ? (y + h0v) : y;
    }
}
__global__ __launch_bounds__(CPBF) void fir_gelu_fb(const float* __restrict__ x,
                                                    const float* __restrict__ kt4,
                                                    float* __restrict__ out) {
    const int h = blockIdx.x;
    const int logical = ((h & 7) << 8) | (h >> 3);
    const int tile = logical & 255, sl = logical >> 8;
    const int cb = sl & 1, b = sl >> 1;
    const int c = cb * CPBF + threadIdx.x;
    const int n0 = tile * RINGF;
    const float* xb = x + (size_t)b * LSEQ * CH + c;
    const float4* kt4v = (const float4*)kt4;
    float acc[RINGF]; float ring[RINGF]; float px[2][8]; float kbuf[2][8];
#pragma unroll
    for (int r = 0; r < RINGF; ++r) acc[r] = 0.0f;
#pragma unroll
    for (int i = 0; i < RINGF; ++i) ring[i] = xb[(size_t)(n0 + i) * CH];
    {
        const float4 ka = kt4v[(size_t)0 * CH + c];
        const float4 kb = kt4v[(size_t)1 * CH + c];
        kbuf[0][0] = ka.x; kbuf[0][1] = ka.y; kbuf[0][2] = ka.z; kbuf[0][3] = ka.w;
        kbuf[0][4] = kb.x; kbuf[0][5] = kb.y; kbuf[0][6] = kb.z; kbuf[0][7] = kb.w;
#pragma unroll
        for (int g2 = 0; g2 < 8; ++g2) {
            const int m = n0 - 1 - g2;
            px[0][g2] = (m >= 0) ? xb[(size_t)m * CH] : 0.0f;
        }
    }
    for (int tb = 0; tb < KTAP; tb += RINGF) {
#pragma unroll
        for (int q = 0; q < 4; ++q) {
            const int cur = q & 1, nxt = cur ^ 1;
            const int tn = tb + 8 * (q + 1);
            if (tn < KTAP) {
                const float4 ka = kt4v[(size_t)(tn >> 2) * CH + c];
                const float4 kb = kt4v[(size_t)((tn >> 2) + 1) * CH + c];
                kbuf[nxt][0] = ka.x; kbuf[nxt][1] = ka.y; kbuf[nxt][2] = ka.z; kbuf[nxt][3] = ka.w;
                kbuf[nxt][4] = kb.x; kbuf[nxt][5] = kb.y; kbuf[nxt][6] = kb.z; kbuf[nxt][7] = kb.w;
#pragma unroll
                for (int g2 = 0; g2 < 8; ++g2) {
                    const int m = n0 - tn - 1 - g2;
                    px[nxt][g2] = (m >= 0) ? xb[(size_t)m * CH] : 0.0f;
                }
            }
#pragma unroll
            for (int g2 = 0; g2 < 8; ++g2) {
                const int tq = 8 * q + g2;
                const float kv = kbuf[cur][g2];
#pragma unroll
                for (int r = 0; r < RINGF; ++r)
                    acc[r] = fmaf(kv, ring[(r - tq) & (RINGF - 1)], acc[r]);
                ring[(RINGF - 1 - tq) & (RINGF - 1)] = px[cur][g2];
            }
        }
    }
    float* ob = out + ((size_t)b * LSEQ + n0) * CH + c;
#pragma unroll
    for (int r = 0; r < RINGF; ++r) {
        const float y = acc[r];
        const float m2 = y * y;
        const float wv = fmaf(m2, 0.14270963f, 1.5957691f);
        const float e = __expf(y * wv);
        const float rc = __builtin_amdgcn_rcpf(e + 1.0f);
        ob[(size_t)r * CH] = y - y * rc;
    }
}

extern "C" void kernel_launch(void* const* d_in, const int* in_sizes, int n_in,
                              void* d_out, int out_size, void* d_ws, size_t ws_size,
                              hipStream_t stream) {
    const float* x  = (const float*)d_in[0];
    const float* A  = (const float*)d_in[1];
    const float* B  = (const float*)d_in[2];
    const float* h0 = (const float*)d_in[3];
    float* out = (float*)d_out;

    if (ws_size >= WS_NEED) {
        _Float16* afr = (_Float16*)d_ws;
        rtf_afrag<<<dim3(CH / 4), dim3(256), 0, stream>>>(A, B, h0, afr);
        fir_mfma<<<dim3(1024), dim3(256), 0, stream>>>(x, afr, out);
    } else {
        float* kt4 = (float*)d_ws;  // 512 KB
        rtf_impulse_fb<<<dim3(CH), dim3(ORDER), 0, stream>>>(A, B, h0, kt4);
        fir_gelu_fb<<<dim3((LSEQ / RINGF) * (CH / CPBF) * NBATCH), dim3(CPBF), 0, stream>>>(x, kt4, out);
    }
}

// Round 11
// 61.609 us; speedup vs baseline: 1.0353x; 1.0353x over previous
//
#include <hip/hip_runtime.h>
#include <stdint.h>

// Problem constants: x (4, 8192, 512) f32, A/B (512, 64), h0 scalar.
#define NBATCH 4
#define LSEQ   8192
#define CH     512
#define ORDER  64
#define KTAP   256           // validated R3-R9: tail < 1e-5, threshold 5.86e-3
#define NW     9             // windows T0_w = 32w+15 cover t in [0,256) once/row

typedef _Float16 half8 __attribute__((ext_vector_type(8)));
typedef __fp16   fp16x2 __attribute__((ext_vector_type(2)));
typedef float    f32x4 __attribute__((ext_vector_type(4)));

#define AFRAG_HALFS  ((size_t)CH * NW * 64 * 8)        // 4.7 MB
#define WS_NEED      (AFRAG_HALFS * 2)

// ---- persistent fir geometry -----------------------------------------------
// Block = 16 ch x 4096 n x 1 batch; grid 256 = 1 block/CU; 512 threads.
// xs[lc][idx] f16, idx = row - (nbase-271), idx in [0,4368); row width padded
// to 4376 halves (8752 B): 16B-aligned b128 reads (idx0 % 8 == 0 by
// construction) and ch-stride 12 banks (stage writes spread).
#define ROWS  4368
#define XW    4376
#define XWB   8752
#define LOUT_OFF (16 * XWB)           // 140032
#define LOWB  1040                    // 260 f32 per lds_out row
#define SMEMB (LOUT_OFF + 16 * LOWB)  // 156672 <= 163840
#define S1_PAIRS 1216                 // stage1 covers idx [0,2432): tiles 0..7
                                      // (tile 7 max idx 2319 < 2432)
#define PAIRS_TOT 2184                // ROWS/2

__device__ __forceinline__ uint32_t pkrtz(float lo, float hi) {
    fp16x2 v = __builtin_amdgcn_cvt_pkrtz(lo, hi);
    return __builtin_bit_cast(uint32_t, v);
}

// ---------------------------------------------------------------------------
// Kernel 1: IIR impulse response -> per-channel MFMA A-fragments (proven R7-R9).
//   A_w[i][k] = Kx[32w+15+i-k], lane l: i=l&15, k=8*(l>>4)+e; h0 folded into
//   Kx[0]; Kx zero outside [0,KTAP). 4 channels/block, one wave each.
// ---------------------------------------------------------------------------
__global__ __launch_bounds__(256) void rtf_afrag(const float* __restrict__ A,
                                                 const float* __restrict__ B,
                                                 const float* __restrict__ h0,
                                                 _Float16* __restrict__ afr) {
    __shared__ float Ksh[4][KTAP];
    const int wv = threadIdx.x >> 6, lane = threadIdx.x & 63;
    const int c  = blockIdx.x * 4 + wv;
    const float a  = A[c * ORDER + lane];
    const float bc = B[c * ORDER + lane];
    const float h0v = h0[0];
    float s = 0.0f;
    for (int t = 0; t < KTAP; ++t) {
        const float s1 = __shfl(s, 0);
        const float bt = (t < ORDER) ? __shfl(bc, t) : 0.0f;
        const float y  = bt + s1;
        float su = __shfl_down(s, 1);
        if (lane == ORDER - 1) su = 0.0f;
        s = su - a * y;
        if (lane == 0) Ksh[wv][t] = (t == 0) ? (y + h0v) : y;
    }
    __syncthreads();
    const int i = lane & 15, g = lane >> 4;
    for (int w = 0; w < NW; ++w) {
        half8 hv;
#pragma unroll
        for (int e = 0; e < 8; ++e) {
            const int t = 32 * w + 15 + i - 8 * g - e;
            hv[e] = (_Float16)((t >= 0 && t < KTAP) ? Ksh[wv][t] : 0.0f);
        }
        *reinterpret_cast<half8*>(afr + ((size_t)(c * NW + w) * 64 + lane) * 8) = hv;
    }
}

// ---------------------------------------------------------------------------
// Kernel 2: persistent banded-Toeplitz MFMA FIR + gelu.
// 256 blocks (1/CU), 512 threads (8 waves, 2 ch/wave). Whole x window for the
// block's 16ch x 4096n slab lives in LDS (staged once, f16 pair-packed);
// A-fragments live in registers for the entire kernel (18 half8/wave).
// Stage1 (idx<2432) up-front with all loads issued before writes; stage2
// trickles in T14-style (issue chunk ti+1, write chunk ti) under tiles 0..7;
// chunk ti first read at tile ti+8 (>=2 barriers in between -> race-safe).
// Per tile: 18 ds_read_b128 + 18 MFMA -> gelu -> lds_out -> 64B float4 stores.
// ---------------------------------------------------------------------------
__global__ __launch_bounds__(512) void fir_persist(const float* __restrict__ x,
                                                   const _Float16* __restrict__ afr,
                                                   float* __restrict__ out) {
    __shared__ __align__(16) char smem[SMEMB];
    // decode: XCD = bid&7 = chgrp&7 -> 4 chgrps per XCD, afr slab L2-resident
    const int bid   = blockIdx.x;
    const int chgrp = bid & 31;
    const int slice = bid >> 5;          // 0..7
    const int nh    = slice & 1;
    const int bb    = slice >> 1;
    const int nbase = nh * 4096;
    const int c0    = chgrp * 16;

    const int wid  = threadIdx.x >> 6;   // 0..7
    const int lane = threadIdx.x & 63;
    const int ca   = c0 + 2 * wid;       // wave's channel pair
    const int cb_  = ca + 1;

    // ---- A-fragments into registers (18 x 16B global loads, issued first) ----
    half8 afA[NW], afB[NW];
#pragma unroll
    for (int w = 0; w < NW; ++w) {
        afA[w] = *reinterpret_cast<const half8*>(afr + (((size_t)ca  * NW + w) * 64 + lane) * 8);
        afB[w] = *reinterpret_cast<const half8*>(afr + (((size_t)cb_ * NW + w) * 64 + lane) * 8);
    }

    // ---- stage1: idx [0,2432), all loads issued, then all writes ----
    const int q  = threadIdx.x & 3;      // ch quad
    const int pr = threadIdx.x >> 2;     // 0..127 pair slot
    const float* xsrc = x + (size_t)bb * LSEQ * CH + c0 + q * 4;
    f32x4 L0[10], L1[10];
#pragma unroll
    for (int i = 0; i < 10; ++i) {
        const int p  = pr + 128 * i;
        const int r0 = nbase - 271 + 2 * p;
        f32x4 z = {0.f, 0.f, 0.f, 0.f};
        L0[i] = z; L1[i] = z;
        if (p < S1_PAIRS) {
            if ((unsigned)r0 < LSEQ)       L0[i] = *reinterpret_cast<const f32x4*>(xsrc + (size_t)r0 * CH);
            if ((unsigned)(r0 + 1) < LSEQ) L1[i] = *reinterpret_cast<const f32x4*>(xsrc + (size_t)(r0 + 1) * CH);
        }
    }
    // issue stage2 chunk 0 (covered by stage1 writes + barrier)
    f32x4 s0 = {0.f, 0.f, 0.f, 0.f}, s1 = s0;
    {
        const int p  = S1_PAIRS + pr;
        const int r0 = nbase - 271 + 2 * p;
        if ((unsigned)r0 < LSEQ)       s0 = *reinterpret_cast<const f32x4*>(xsrc + (size_t)r0 * CH);
        if ((unsigned)(r0 + 1) < LSEQ) s1 = *reinterpret_cast<const f32x4*>(xsrc + (size_t)(r0 + 1) * CH);
    }
#pragma unroll
    for (int i = 0; i < 10; ++i) {
        const int p = pr + 128 * i;
        if (p < S1_PAIRS) {
            char* wb = smem + (size_t)(4 * q) * XWB + 4 * p;
            *reinterpret_cast<uint32_t*>(wb + 0 * XWB) = pkrtz(L0[i][0], L1[i][0]);
            *reinterpret_cast<uint32_t*>(wb + 1 * XWB) = pkrtz(L0[i][1], L1[i][1]);
            *reinterpret_cast<uint32_t*>(wb + 2 * XWB) = pkrtz(L0[i][2], L1[i][2]);
            *reinterpret_cast<uint32_t*>(wb + 3 * XWB) = pkrtz(L0[i][3], L1[i][3]);
        }
    }
    __syncthreads();

    // ---- main loop: 16 tiles of 256 n ----
    const int jb = 16 * (lane & 15);          // 16j
    const int gb = 8 * (lane >> 4);           // 8g
    const char* xrowA = smem + (size_t)(2 * wid + 0) * XWB;
    const char* xrowB = smem + (size_t)(2 * wid + 1) * XWB;
    float* loutA = reinterpret_cast<float*>(smem + LOUT_OFF + (size_t)(2 * wid + 0) * LOWB);
    float* loutB = reinterpret_cast<float*>(smem + LOUT_OFF + (size_t)(2 * wid + 1) * LOWB);
    const int nf  = jb + 4 * (lane >> 4);     // 16j + 4g
    const int cq  = threadIdx.x & 3;
    const int nr0 = threadIdx.x >> 2;         // 0..127

    for (int ti = 0; ti < 16; ++ti) {
        // stage2: write chunk ti (loads issued ~1 tile ago), issue chunk ti+1
        if (ti < 8) {
            const int p = S1_PAIRS + 128 * ti + pr;
            if (p < PAIRS_TOT) {
                char* wb = smem + (size_t)(4 * q) * XWB + 4 * p;
                *reinterpret_cast<uint32_t*>(wb + 0 * XWB) = pkrtz(s0[0], s1[0]);
                *reinterpret_cast<uint32_t*>(wb + 1 * XWB) = pkrtz(s0[1], s1[1]);
                *reinterpret_cast<uint32_t*>(wb + 2 * XWB) = pkrtz(s0[2], s1[2]);
                *reinterpret_cast<uint32_t*>(wb + 3 * XWB) = pkrtz(s0[3], s1[3]);
            }
            if (ti < 7) {
                const int pn = S1_PAIRS + 128 * (ti + 1) + pr;
                const int r0 = nbase - 271 + 2 * pn;
                f32x4 z = {0.f, 0.f, 0.f, 0.f}; s0 = z; s1 = z;
                if (pn < PAIRS_TOT) {
                    if ((unsigned)r0 < LSEQ)       s0 = *reinterpret_cast<const f32x4*>(xsrc + (size_t)r0 * CH);
                    if ((unsigned)(r0 + 1) < LSEQ) s1 = *reinterpret_cast<const f32x4*>(xsrc + (size_t)(r0 + 1) * CH);
                }
            }
        }
        // compute: 18 ds_read_b128 + 18 MFMA (B-frag per channel; A in regs)
        f32x4 aca = {0.f, 0.f, 0.f, 0.f}, acb = aca;
        const int bbase = 512 * ti + 2 * (jb + gb + 256);
#pragma unroll
        for (int w = 0; w < NW; ++w) {
            const int byt = bbase - 64 * w;
            const half8 bva = *reinterpret_cast<const half8*>(xrowA + byt);
            const half8 bvb = *reinterpret_cast<const half8*>(xrowB + byt);
            aca = __builtin_amdgcn_mfma_f32_16x16x32_f16(afA[w], bva, aca, 0, 0, 0);
            acb = __builtin_amdgcn_mfma_f32_16x16x32_f16(afB[w], bvb, acb, 0, 0, 0);
        }
        // epilogue: gelu -> lds_out -> coalesced float4 stores
        f32x4 oa, ob;
#pragma unroll
        for (int r = 0; r < 4; ++r) {
            float y  = aca[r];
            float wv = fmaf(y * y, 0.14270963f, 1.5957691f);
            float e  = __expf(y * wv);
            oa[r] = y - y * __builtin_amdgcn_rcpf(e + 1.0f);
            y  = acb[r];
            wv = fmaf(y * y, 0.14270963f, 1.5957691f);
            e  = __expf(y * wv);
            ob[r] = y - y * __builtin_amdgcn_rcpf(e + 1.0f);
        }
        *reinterpret_cast<f32x4*>(loutA + nf) = oa;
        *reinterpret_cast<f32x4*>(loutB + nf) = ob;
        __syncthreads();
        float* obp = out + ((size_t)bb * LSEQ + nbase + 256 * ti) * CH + c0 + 4 * cq;
#pragma unroll
        for (int pass = 0; pass < 2; ++pass) {
            const int nr = nr0 + 128 * pass;
            f32x4 o;
            o[0] = *reinterpret_cast<const float*>(smem + LOUT_OFF + (size_t)(4 * cq + 0) * LOWB + 4 * nr);
            o[1] = *reinterpret_cast<const float*>(smem + LOUT_OFF + (size_t)(4 * cq + 1) * LOWB + 4 * nr);
            o[2] = *reinterpret_cast<const float*>(smem + LOUT_OFF + (size_t)(4 * cq + 2) * LOWB + 4 * nr);
            o[3] = *reinterpret_cast<const float*>(smem + LOUT_OFF + (size_t)(4 * cq + 3) * LOWB + 4 * nr);
            *reinterpret_cast<f32x4*>(obp + (size_t)nr * CH) = o;
        }
        __syncthreads();
    }
}

// ======================== FALLBACK (R5, proven 138us) =======================
#define RINGF 32
#define CPBF  256
__global__ __launch_bounds__(ORDER) void rtf_impulse_fb(const float* __restrict__ A,
                                                        const float* __restrict__ B,
                                                        const float* __restrict__ h0,
                                                        float* __restrict__ kt4) {
    const int c = blockIdx.x, lane = threadIdx.x;
    const float a = A[c * ORDER + lane], bc = B[c * ORDER + lane], h0v = h0[0];
    float s = 0.0f;
    for (int t = 0; t < KTAP; ++t) {
        const float s1 = __shfl(s, 0);
        const float bt = (t < ORDER) ? __shfl(bc, t) : 0.0f;
        const float y  = bt + s1;
        float su = __shfl_down(s, 1);
        if (lane == ORDER - 1) su = 0.0f;
        s = su - a * y;
        if (lane == 0) kt4[((size_t)(t >> 2) * CH + c) * 4 + (t & 3)] = (t == 0) ? (y + h0v) : y;
    }
}
__global__ __launch_bounds__(CPBF) void fir_gelu_fb(const float* __restrict__ x,
                                                    const float* __restrict__ kt4,
                                                    float* __restrict__ out) {
    const int h = blockIdx.x;
    const int logical = ((h & 7) << 8) | (h >> 3);
    const int tile = logical & 255, sl = logical >> 8;
    const int cb = sl & 1, b = sl >> 1;
    const int c = cb * CPBF + threadIdx.x;
    const int n0 = tile * RINGF;
    const float* xb = x + (size_t)b * LSEQ * CH + c;
    const float4* kt4v = (const float4*)kt4;
    float acc[RINGF]; float ring[RINGF]; float px[2][8]; float kbuf[2][8];
#pragma unroll
    for (int r = 0; r < RINGF; ++r) acc[r] = 0.0f;
#pragma unroll
    for (int i = 0; i < RINGF; ++i) ring[i] = xb[(size_t)(n0 + i) * CH];
    {
        const float4 ka = kt4v[(size_t)0 * CH + c];
        const float4 kb = kt4v[(size_t)1 * CH + c];
        kbuf[0][0] = ka.x; kbuf[0][1] = ka.y; kbuf[0][2] = ka.z; kbuf[0][3] = ka.w;
        kbuf[0][4] = kb.x; kbuf[0][5] = kb.y; kbuf[0][6] = kb.z; kbuf[0][7] = kb.w;
#pragma unroll
        for (int g2 = 0; g2 < 8; ++g2) {
            const int m = n0 - 1 - g2;
            px[0][g2] = (m >= 0) ? xb[(size_t)m * CH] : 0.0f;
        }
    }
    for (int tb = 0; tb < KTAP; tb += RINGF) {
#pragma unroll
        for (int qq = 0; qq < 4; ++qq) {
            const int cur = qq & 1, nxt = cur ^ 1;
            const int tn = tb + 8 * (qq + 1);
            if (tn < KTAP) {
                const float4 ka = kt4v[(size_t)(tn >> 2) * CH + c];
                const float4 kb = kt4v[(size_t)((tn >> 2) + 1) * CH + c];
                kbuf[nxt][0] = ka.x; kbuf[nxt][1] = ka.y; kbuf[nxt][2] = ka.z; kbuf[nxt][3] = ka.w;
                kbuf[nxt][4] = kb.x; kbuf[nxt][5] = kb.y; kbuf[nxt][6] = kb.z; kbuf[nxt][7] = kb.w;
#pragma unroll
                for (int g2 = 0; g2 < 8; ++g2) {
                    const int m = n0 - tn - 1 - g2;
                    px[nxt][g2] = (m >= 0) ? xb[(size_t)m * CH] : 0.0f;
                }
            }
#pragma unroll
            for (int g2 = 0; g2 < 8; ++g2) {
                const int tq = 8 * qq + g2;
                const float kv = kbuf[cur][g2];
#pragma unroll
                for (int r = 0; r < RINGF; ++r)
                    acc[r] = fmaf(kv, ring[(r - tq) & (RINGF - 1)], acc[r]);
                ring[(RINGF - 1 - tq) & (RINGF - 1)] = px[cur][g2];
            }
        }
    }
    float* ob = out + ((size_t)b * LSEQ + n0) * CH + c;
#pragma unroll
    for (int r = 0; r < RINGF; ++r) {
        const float y = acc[r];
        const float wv = fmaf(y * y, 0.14270963f, 1.5957691f);
        const float e = __expf(y * wv);
        ob[(size_t)r * CH] = y - y * __builtin_amdgcn_rcpf(e + 1.0f);
    }
}

extern "C" void kernel_launch(void* const* d_in, const int* in_sizes, int n_in,
                              void* d_out, int out_size, void* d_ws, size_t ws_size,
                              hipStream_t stream) {
    const float* x  = (const float*)d_in[0];
    const float* A  = (const float*)d_in[1];
    const float* B  = (const float*)d_in[2];
    const float* h0 = (const float*)d_in[3];
    float* out = (float*)d_out;

    if (ws_size >= WS_NEED) {
        _Float16* afr = (_Float16*)d_ws;
        rtf_afrag<<<dim3(CH / 4), dim3(256), 0, stream>>>(A, B, h0, afr);
        fir_persist<<<dim3(256), dim3(512), 0, stream>>>(x, afr, out);
    } else {
        float* kt4 = (float*)d_ws;  // 512 KB
        rtf_impulse_fb<<<dim3(CH), dim3(ORDER), 0, stream>>>(A, B, h0, kt4);
        fir_gelu_fb<<<dim3((LSEQ / RINGF) * (CH / CPBF) * NBATCH), dim3(CPBF), 0, stream>>>(x, kt4, out);
    }
}